// Round 7
// baseline (1054.493 us; speedup 1.0000x reference)
//
#include <hip/hip_runtime.h>
#include <hip/hip_bf16.h>

// ---------------- sizes ----------------
// B=16, L=1024, Dm=128, Din=256, N=8, R=8, NBLK=3
#define BB   16
#define LL   1024
#define DM   128
#define DIN  256
#define NST  8
#define NROWS (BB*LL)      // 16384
#define NCH  32            // scan chunks
#define TCH  32            // steps per chunk
#define PSZ  1048576       // B*NCH*DIN*8

static __device__ __forceinline__ float sigmoidf_(float x){ return 1.f/(1.f+expf(-x)); }
static __device__ __forceinline__ float siluf_(float x){ return x/(1.f+expf(-x)); }
static __device__ __forceinline__ unsigned short f2bf(float f){
    union { float f; unsigned u; } v; v.f = f;
    unsigned r = v.u + 0x7fff + ((v.u >> 16) & 1);
    return (unsigned short)(r >> 16);
}

typedef __attribute__((ext_vector_type(8))) short short8;
typedef __attribute__((ext_vector_type(4))) float floatx4;

// ---------------- LayerNorm over last dim 128 ----------------
__global__ __launch_bounds__(64) void ln_kernel(const float* __restrict__ X,
        const float* __restrict__ g, const float* __restrict__ b,
        float* __restrict__ Y, int transpose)
{
    int row = blockIdx.x;
    int t = threadIdx.x;
    float x0 = X[(long)row*DM + t];
    float x1 = X[(long)row*DM + 64 + t];
    float s = x0 + x1, ss = x0*x0 + x1*x1;
    #pragma unroll
    for (int off = 32; off; off >>= 1) { s += __shfl_down(s, off); ss += __shfl_down(ss, off); }
    s = __shfl(s, 0); ss = __shfl(ss, 0);
    float mean = s * (1.f/128.f);
    float var  = ss * (1.f/128.f) - mean*mean;
    float inv  = rsqrtf(var + 1e-5f);
    float y0 = (x0-mean)*inv*g[t]    + b[t];
    float y1 = (x1-mean)*inv*g[64+t] + b[64+t];
    if (!transpose) {
        Y[(long)row*DM + t] = y0;
        Y[(long)row*DM + 64 + t] = y1;
    } else {
        int bb = row >> 10, l = row & 1023;
        Y[((long)(bb*DM) + t)*LL + l] = y0;
        Y[((long)(bb*DM) + 64 + t)*LL + l] = y1;
    }
}

// ---------------- bf16-MFMA GEMM: C[M,N] = A[M,K] @ W[N,K]^T (+S) ----------------
// f32 inputs cast to bf16 during packed-b64 LDS staging; fp32 MFMA accumulate.
// Block 256 = 4 waves; tile MT(M) x 128(N); wave owns MT/4 rows.
template<int K, int MT>
__global__ __launch_bounds__(256) void gemm_bf16(const float* __restrict__ A,
        const float* __restrict__ Wm, const float* __restrict__ S,
        float* __restrict__ C, int N)
{
    constexpr int NMT = MT/64;            // 16-row m-tiles per wave
    __shared__ unsigned short Als[MT][40];
    __shared__ unsigned short Bls[128][40];
    const int tid = threadIdx.x;
    const int m0 = blockIdx.x * MT;
    const int n0 = blockIdx.y * 128;
    const int lane = tid & 63, wv = tid >> 6;
    const int fr = lane & 15, quad = lane >> 4;
    floatx4 acc[NMT][8];
    #pragma unroll
    for (int mt = 0; mt < NMT; mt++)
        #pragma unroll
        for (int nt = 0; nt < 8; nt++) acc[mt][nt] = (floatx4){0.f,0.f,0.f,0.f};
    for (int kc = 0; kc < K; kc += 32) {
        __syncthreads();
        #pragma unroll
        for (int i = 0; i < (MT+128)/32; i++) {
            int u = tid + i*256;
            int row = u >> 3, seg = u & 7;
            const float* src = (row < MT) ? &A[(long)(m0+row)*K + kc + seg*4]
                                          : &Wm[(long)(n0+row-MT)*K + kc + seg*4];
            float4 v4 = *(const float4*)src;
            uint2 pk;
            pk.x = (unsigned)f2bf(v4.x) | ((unsigned)f2bf(v4.y) << 16);
            pk.y = (unsigned)f2bf(v4.z) | ((unsigned)f2bf(v4.w) << 16);
            if (row < MT) *(uint2*)&Als[row][seg*4] = pk;
            else          *(uint2*)&Bls[row-MT][seg*4] = pk;
        }
        __syncthreads();
        short8 af[NMT];
        #pragma unroll
        for (int mt = 0; mt < NMT; mt++)
            af[mt] = *(const short8*)&Als[wv*(16*NMT) + mt*16 + fr][quad*8];
        #pragma unroll
        for (int nt = 0; nt < 8; nt++) {
            short8 bfv = *(const short8*)&Bls[nt*16 + fr][quad*8];
            #pragma unroll
            for (int mt = 0; mt < NMT; mt++)
                acc[mt][nt] = __builtin_amdgcn_mfma_f32_16x16x32_bf16(af[mt], bfv, acc[mt][nt], 0, 0, 0);
        }
    }
    const int rq = quad * 4;
    #pragma unroll
    for (int mt = 0; mt < NMT; mt++)
        #pragma unroll
        for (int nt = 0; nt < 8; nt++)
            #pragma unroll
            for (int r = 0; r < 4; r++) {
                long m = m0 + wv*(16*NMT) + mt*16 + rq + r;
                long n = n0 + nt*16 + fr;
                float v = acc[mt][nt][r];
                if (S) v += S[m*N + n];
                C[m*N + n] = v;
            }
}

// ---------------- depthwise causal conv (k=4) + bias + SiLU ----------------
__global__ __launch_bounds__(256) void dwconv_silu(const float* __restrict__ xz,
        const float* __restrict__ w, const float* __restrict__ bias, float* __restrict__ xc)
{
    int bl = blockIdx.x;            // b*1024 + l
    int d  = threadIdx.x;
    int l  = bl & 1023;
    float w0 = w[d*4+0], w1 = w[d*4+1], w2 = w[d*4+2], w3 = w[d*4+3];
    const float* base = xz + (long)bl*512 + d;
    float acc = bias[d] + w3 * base[0];
    if (l >= 1) acc += w2 * base[-512];
    if (l >= 2) acc += w1 * base[-1024];
    if (l >= 3) acc += w0 * base[-1536];
    xc[(long)bl*DIN + d] = siluf_(acc);
}

// ---------------- x-proj (24 outs) + dt-proj + softplus ----------------
__global__ __launch_bounds__(256) void xproj_dt(const float* __restrict__ xc,
        const float* __restrict__ xproj_w, const float* __restrict__ dt_w,
        const float* __restrict__ dt_b, float* __restrict__ dt_out, float* __restrict__ BC)
{
    __shared__ float xs[DIN];
    __shared__ float xdbl[24];
    int row = blockIdx.x, t = threadIdx.x;
    xs[t] = xc[(long)row*DIN + t];
    __syncthreads();
    if (t < 192) {                       // 24 outputs x 8 lanes
        int e = t >> 3, j = t & 7;
        float p = 0.f;
        for (int k = j; k < DIN; k += 8) p += xs[k] * xproj_w[e*DIN + k];
        p += __shfl_down(p, 4, 8);
        p += __shfl_down(p, 2, 8);
        p += __shfl_down(p, 1, 8);
        if (j == 0) xdbl[e] = p;
    }
    __syncthreads();
    float v = dt_b[t];
    #pragma unroll
    for (int r = 0; r < 8; r++) v += xdbl[r] * dt_w[t*8 + r];
    v = (v > 20.f) ? v : log1pf(expf(v));           // softplus
    dt_out[(long)row*DIN + t] = v;
    if (t < 16) BC[(long)row*16 + t] = xdbl[8 + t]; // B(8) then C(8)
}

// ---------------- chunked selective scan ----------------
__global__ __launch_bounds__(256) void scan_part(const float* __restrict__ dt,
        const float* __restrict__ xc, const float* __restrict__ BC,
        const float* __restrict__ Alog, float* __restrict__ PS)
{
    int b = blockIdx.x, c = blockIdx.y;
    int d = threadIdx.x;
    float a[NST], P[NST], S[NST];
    #pragma unroll
    for (int n = 0; n < NST; n++) { a[n] = -expf(Alog[d*NST + n]); P[n] = 1.f; S[n] = 0.f; }
    int t0 = c*TCH;
    const float* dtp = dt + ((long)b*LL + t0)*DIN + d;
    const float* up  = xc + ((long)b*LL + t0)*DIN + d;
    const float* bc  = BC + ((long)b*LL + t0)*16;
    for (int t = 0; t < TCH; t++) {
        float dtv = dtp[(long)t*DIN];
        float u   = up[(long)t*DIN];
        const float4* bc4 = (const float4*)(bc + t*16);
        float4 B0 = bc4[0], B1 = bc4[1];
        float Bv[NST] = {B0.x,B0.y,B0.z,B0.w,B1.x,B1.y,B1.z,B1.w};
        float dtu = dtv * u;
        #pragma unroll
        for (int n = 0; n < NST; n++) {
            float dA = __expf(dtv * a[n]);
            S[n] = dA * S[n] + dtu * Bv[n];
            P[n] *= dA;
        }
    }
    long o = (((long)b*NCH + c)*DIN + d)*8;
    #pragma unroll
    for (int n = 0; n < NST; n++) { PS[o + n] = P[n]; PS[PSZ + o + n] = S[n]; }
}

__global__ __launch_bounds__(256) void scan_mid(const float* __restrict__ PS,
        float* __restrict__ Hinit)
{
    int b = blockIdx.x;
    int d = threadIdx.x;
    float h[NST] = {};
    for (int c = 0; c < NCH; c++) {
        long o = (((long)b*NCH + c)*DIN + d)*8;
        #pragma unroll
        for (int n = 0; n < NST; n++) {
            Hinit[o + n] = h[n];
            h[n] = PS[o + n] * h[n] + PS[PSZ + o + n];
        }
    }
}

__global__ __launch_bounds__(256) void scan_fin(const float* __restrict__ dt,
        const float* __restrict__ xc, const float* __restrict__ BC,
        const float* __restrict__ xz, const float* __restrict__ Alog,
        const float* __restrict__ Dp, const float* __restrict__ Hinit,
        float* __restrict__ yg)
{
    int b = blockIdx.x, c = blockIdx.y;
    int d = threadIdx.x;
    float a[NST], h[NST];
    long o = (((long)b*NCH + c)*DIN + d)*8;
    #pragma unroll
    for (int n = 0; n < NST; n++) { a[n] = -expf(Alog[d*NST + n]); h[n] = Hinit[o + n]; }
    float Dpd = Dp[d];
    int t0 = c*TCH;
    const float* dtp = dt + ((long)b*LL + t0)*DIN + d;
    const float* up  = xc + ((long)b*LL + t0)*DIN + d;
    const float* bc  = BC + ((long)b*LL + t0)*16;
    const float* zp  = xz + ((long)b*LL + t0)*512 + 256 + d;
    float* yo = yg + ((long)b*LL + t0)*DIN + d;
    for (int t = 0; t < TCH; t++) {
        float dtv = dtp[(long)t*DIN];
        float u   = up[(long)t*DIN];
        const float4* bc4 = (const float4*)(bc + t*16);
        float4 B0 = bc4[0], B1 = bc4[1], C0 = bc4[2], C1 = bc4[3];
        float Bv[NST] = {B0.x,B0.y,B0.z,B0.w,B1.x,B1.y,B1.z,B1.w};
        float Cv[NST] = {C0.x,C0.y,C0.z,C0.w,C1.x,C1.y,C1.z,C1.w};
        float dtu = dtv * u;
        float y = 0.f;
        #pragma unroll
        for (int n = 0; n < NST; n++) {
            float dA = __expf(dtv * a[n]);
            h[n] = dA * h[n] + dtu * Bv[n];
            y += h[n] * Cv[n];
        }
        y += u * Dpd;
        float z = zp[(long)t*512];
        yo[(long)t*DIN] = y * siluf_(z);
    }
}

// ---------------- phase-decomposed up2+3x3 conv ----------------
__global__ void prep_weff(const float* __restrict__ Wr, float* __restrict__ We, int total)
{
    int t = blockIdx.x*256 + threadIdx.x;
    if (t >= total) return;
    float w[3][3];
    #pragma unroll
    for (int a = 0; a < 3; a++)
        #pragma unroll
        for (int c = 0; c < 3; c++) w[a][c] = Wr[(long)t*9 + a*3 + c];
    float cw[2][3][2];
    #pragma unroll
    for (int ky = 0; ky < 3; ky++) {
        cw[0][ky][0] = w[ky][0];           cw[0][ky][1] = w[ky][1] + w[ky][2];
        cw[1][ky][0] = w[ky][0] + w[ky][1]; cw[1][ky][1] = w[ky][2];
    }
    float* o = We + (long)t*16;   // [py][px][i*2+j]
    #pragma unroll
    for (int px = 0; px < 2; px++) {
        o[0*8+px*4+0] = cw[px][0][0];               o[0*8+px*4+1] = cw[px][0][1];
        o[0*8+px*4+2] = cw[px][1][0]+cw[px][2][0];  o[0*8+px*4+3] = cw[px][1][1]+cw[px][2][1];
        o[1*8+px*4+0] = cw[px][0][0]+cw[px][1][0];  o[1*8+px*4+1] = cw[px][0][1]+cw[px][1][1];
        o[1*8+px*4+2] = cw[px][2][0];               o[1*8+px*4+3] = cw[px][2][1];
    }
}

// Block: 16 out rows x 64 out cols x 16 oc. Thread: rel=tid&63 (out col),
// ocq=tid>>6 (4 oc), 16 rows/thread -> weight LDS reads amortized 2x vs v1.
template<int CIN, int INW, int ICB>
__global__ __launch_bounds__(256) void conv_up2_phase(const float* __restrict__ X,
        const float* __restrict__ We, const float* __restrict__ bias,
        const float* __restrict__ bng, const float* __restrict__ bnb,
        const float* __restrict__ bnm, const float* __restrict__ bnv,
        float* __restrict__ Y, int relu_first, int COUT)
{
    constexpr int OUTW = 2*INW;
    constexpr int NXT  = OUTW/64;
    __shared__ float  src[ICB][10][34];
    __shared__ float4 wf[ICB][16][4];      // [ic][oc_local][py*2+px] -> (i,j) float4
    const int ys = blockIdx.x / NXT, xt = blockIdx.x % NXT;
    const int y0 = ys*16, x0 = xt*64;
    const int ocb = blockIdx.y * 16;
    const int b = blockIdx.z;
    const int tid = threadIdx.x;
    const int rel = tid & 63, ocq = tid >> 6;
    const int Xc = x0 + rel;
    const int px = Xc & 1;
    const int lcp = (rel >> 1) + px;       // staged col of (j=0) tap
    const int ry0 = y0 >> 1;
    float acc[16][4] = {};
    for (int ic0 = 0; ic0 < CIN; ic0 += ICB) {
        __syncthreads();
        for (int i = tid; i < ICB*10*34; i += 256) {
            int ic = i / 340, rem = i % 340;
            int rr = rem / 34, cc = rem % 34;
            int gr = ry0 - 1 + rr, gc = (x0>>1) - 1 + cc;
            float v = 0.f;
            if ((unsigned)gr < (unsigned)INW && (unsigned)gc < (unsigned)INW)
                v = X[((long)(b*CIN + ic0+ic))*(INW*INW) + gr*INW + gc];
            src[ic][rr][cc] = v;
        }
        for (int i = tid; i < ICB*256; i += 256) {
            int ic = i >> 8, rem = i & 255;
            int ol = rem >> 4, k = rem & 15;
            ((float*)&wf[ic][ol][0])[k] = We[((long)(ocb+ol)*CIN + ic0+ic)*16 + k];
        }
        __syncthreads();
        for (int ic = 0; ic < ICB; ic++) {
            float s[10][2];
            #pragma unroll
            for (int r = 0; r < 10; r++) { s[r][0] = src[ic][r][lcp]; s[r][1] = src[ic][r][lcp+1]; }
            #pragma unroll
            for (int ol = 0; ol < 4; ol++) {
                float4 w0 = wf[ic][(ocq<<2)+ol][px];       // py=0
                float4 w1 = wf[ic][(ocq<<2)+ol][2+px];     // py=1
                #pragma unroll
                for (int p = 0; p < 8; p++) {
                    acc[2*p  ][ol] += w0.x*s[p  ][0] + w0.y*s[p  ][1] + w0.z*s[p+1][0] + w0.w*s[p+1][1];
                    acc[2*p+1][ol] += w1.x*s[p+1][0] + w1.y*s[p+1][1] + w1.z*s[p+2][0] + w1.w*s[p+2][1];
                }
            }
        }
    }
    #pragma unroll
    for (int ol = 0; ol < 4; ol++) {
        int oc = ocb + (ocq<<2) + ol;
        float bi = bias[oc];
        float sc = bng[oc] * rsqrtf(bnv[oc] + 1e-5f);
        float sh = bnb[oc] - bnm[oc]*sc;
        #pragma unroll
        for (int yy = 0; yy < 16; yy++) {
            float v = acc[yy][ol] + bi;
            v = relu_first ? (fmaxf(v, 0.f)*sc + sh) : fmaxf(v*sc + sh, 0.f);
            Y[((long)(b*COUT + oc))*(OUTW*OUTW) + (long)(y0+yy)*OUTW + Xc] = v;
        }
    }
}

// ---------------- CCE gate partials (tiled matvec) ----------------
__global__ __launch_bounds__(256) void cce_gate_partial(const float* __restrict__ ox,
        const float* __restrict__ oy, const float* __restrict__ w1,
        float* __restrict__ pmax, float* __restrict__ psum)
{
    __shared__ float xs[32*512];
    __shared__ float wl[32*32];
    __shared__ float rmx[4][32], rsm[4][32];
    const int sg = blockIdx.x;    // 0..15 pixel group (1024 px each)
    const int dir = blockIdx.y, b = blockIdx.z;
    const float* X = (dir == 0 ? ox : oy) + (long)b*524288;
    const int t = threadIdx.x;
    for (int i = t; i < 1024; i += 256) { int oc = i >> 5, ic = i & 31; wl[ic*32 + oc] = w1[i]; }
    const int ocg = t & 3, pslot = t >> 2;
    const int oc0 = ocg*8;
    float mx[8], sm[8];
    #pragma unroll
    for (int j = 0; j < 8; j++) { mx[j] = -1e30f; sm[j] = 0.f; }
    const int base = sg*1024;
    for (int tile = 0; tile < 2; tile++) {
        __syncthreads();
        const int p0 = base + tile*512;
        for (int i = t*4; i < 32*512; i += 1024) {
            int ic = i >> 9, px = i & 511;
            *(float4*)&xs[ic*512 + px] = *(const float4*)&X[(long)ic*16384 + p0 + px];
        }
        __syncthreads();
        float acc[8][8];
        #pragma unroll
        for (int p = 0; p < 8; p++)
            #pragma unroll
            for (int j = 0; j < 8; j++) acc[p][j] = 0.f;
        #pragma unroll
        for (int ic = 0; ic < 32; ic++) {
            float4 x0 = *(const float4*)&xs[ic*512 + pslot*4];
            float4 x1 = *(const float4*)&xs[ic*512 + 256 + pslot*4];
            float4 wa = *(const float4*)&wl[ic*32 + oc0];
            float4 wb = *(const float4*)&wl[ic*32 + oc0 + 4];
            float xv[8] = {x0.x,x0.y,x0.z,x0.w,x1.x,x1.y,x1.z,x1.w};
            float wv[8] = {wa.x,wa.y,wa.z,wa.w,wb.x,wb.y,wb.z,wb.w};
            #pragma unroll
            for (int p = 0; p < 8; p++)
                #pragma unroll
                for (int j = 0; j < 8; j++)
                    acc[p][j] += xv[p]*wv[j];
        }
        #pragma unroll
        for (int p = 0; p < 8; p++)
            #pragma unroll
            for (int j = 0; j < 8; j++) { mx[j] = fmaxf(mx[j], acc[p][j]); sm[j] += acc[p][j]; }
    }
    #pragma unroll
    for (int j = 0; j < 8; j++) {
        #pragma unroll
        for (int off = 32; off >= 4; off >>= 1) {
            mx[j] = fmaxf(mx[j], __shfl_down(mx[j], off));
            sm[j] += __shfl_down(sm[j], off);
        }
    }
    const int wave = t >> 6, lane = t & 63;
    __syncthreads();
    if (lane < 4) {
        #pragma unroll
        for (int j = 0; j < 8; j++) { rmx[wave][lane*8+j] = mx[j]; rsm[wave][lane*8+j] = sm[j]; }
    }
    __syncthreads();
    if (t < 32) {
        float M = fmaxf(fmaxf(rmx[0][t], rmx[1][t]), fmaxf(rmx[2][t], rmx[3][t]));
        float S = rsm[0][t] + rsm[1][t] + rsm[2][t] + rsm[3][t];
        long idx = ((long)(dir*16 + b)*32 + t)*16 + sg;
        pmax[idx] = M; psum[idx] = S;
    }
}

__global__ void cce_gate_finish(const float* __restrict__ pmax, const float* __restrict__ psum,
                                float* __restrict__ gates)
{
    int i = blockIdx.x*64 + threadIdx.x;   // 1024 = 2*16*32
    if (i < 1024) {
        float M = -1e30f, S = 0.f;
        #pragma unroll
        for (int sg = 0; sg < 16; sg++) { M = fmaxf(M, pmax[i*16+sg]); S += psum[i*16+sg]; }
        gates[i] = sigmoidf_(M + S*(1.f/16384.f));
    }
}

// ---------------- CCE add ----------------
__global__ __launch_bounds__(256) void cce_add(const float* __restrict__ ox,
        const float* __restrict__ oy, const float* __restrict__ w2,
        const float* __restrict__ gates, float* __restrict__ v)
{
    __shared__ float w[32][32];
    int t = threadIdx.x;
    int b = blockIdx.y;
    int s = blockIdx.x*256 + t;
    for (int i = t; i < 1024; i += 256) w[i>>5][i&31] = w2[i];
    __syncthreads();
    const float* xb = ox + (long)b*524288;
    const float* yb = oy + (long)b*524288;
    float r1[32] = {}, r2[32] = {};
    for (int ic = 0; ic < 32; ic++) {
        float xv = xb[(long)ic*16384 + s];
        float yv = yb[(long)ic*16384 + s];
        #pragma unroll
        for (int oc = 0; oc < 32; oc++) { r1[oc] += w[oc][ic]*yv; r2[oc] += w[oc][ic]*xv; }
    }
    float* vb = v + (long)b*524288;
    const float* g1 = gates + b*32;
    const float* g2 = gates + 512 + b*32;
    #pragma unroll
    for (int oc = 0; oc < 32; oc++)
        vb[(long)oc*16384 + s] += g1[oc]*r1[oc] + g2[oc]*r2[oc];
}

// ---------------- conv3 3x3 (32->1) + sigmoid ----------------
__global__ __launch_bounds__(256) void conv3_sig(const float* __restrict__ v,
        const float* __restrict__ w3, const float* __restrict__ b3, float* __restrict__ out)
{
    __shared__ float w[288];
    int t = threadIdx.x;
    for (int i = t; i < 288; i += 256) w[i] = w3[i];
    __syncthreads();
    int b = blockIdx.y;
    int y = blockIdx.x*2 + (t >> 7);
    int x = t & 127;
    const float* vb = v + (long)b*524288;
    float acc = b3[0];
    for (int ic = 0; ic < 32; ic++) {
        const float* p = vb + (long)ic*16384;
        #pragma unroll
        for (int ky = 0; ky < 3; ky++) {
            int yy = y + ky - 1;
            if ((unsigned)yy >= 128u) continue;
            #pragma unroll
            for (int kx = 0; kx < 3; kx++) {
                int xx = x + kx - 1;
                if ((unsigned)xx >= 128u) continue;
                acc += w[ic*9 + ky*3 + kx] * p[yy*128 + xx];
            }
        }
    }
    out[(long)b*16384 + y*128 + x] = sigmoidf_(acc);
}

// ---------------- launch ----------------
extern "C" void kernel_launch(void* const* d_in, const int* in_sizes, int n_in,
                              void* d_out, int out_size, void* d_ws, size_t ws_size,
                              hipStream_t stream)
{
    const float* fused_in = (const float*)d_in[0];
    const float* orig_x   = (const float*)d_in[1];
    const float* orig_y   = (const float*)d_in[2];
    const float* m_ln_g   = (const float*)d_in[3];
    const float* m_ln_b   = (const float*)d_in[4];
    const float* m_in_w   = (const float*)d_in[5];
    const float* m_conv_w = (const float*)d_in[6];
    const float* m_conv_b = (const float*)d_in[7];
    const float* m_xproj_w= (const float*)d_in[8];
    const float* m_dt_w   = (const float*)d_in[9];
    const float* m_dt_b   = (const float*)d_in[10];
    const float* m_Alog   = (const float*)d_in[11];
    const float* m_D      = (const float*)d_in[12];
    const float* m_out_w  = (const float*)d_in[13];
    const float* lnf_g    = (const float*)d_in[14];
    const float* lnf_b    = (const float*)d_in[15];
    const float* c1_w     = (const float*)d_in[16];
    const float* c1_b     = (const float*)d_in[17];
    const float* bn1_g    = (const float*)d_in[18];
    const float* bn1_b    = (const float*)d_in[19];
    const float* bn1_m    = (const float*)d_in[20];
    const float* bn1_v    = (const float*)d_in[21];
    const float* c2_w     = (const float*)d_in[22];
    const float* c2_b     = (const float*)d_in[23];
    const float* bn2_g    = (const float*)d_in[24];
    const float* bn2_b    = (const float*)d_in[25];
    const float* bn2_m    = (const float*)d_in[26];
    const float* bn2_v    = (const float*)d_in[27];
    const float* cce_w1   = (const float*)d_in[28];
    const float* cce_w2   = (const float*)d_in[29];
    const float* c3_w     = (const float*)d_in[30];
    const float* c3_b     = (const float*)d_in[31];

    float* W = (float*)d_ws;
    float* fusedA = W;                    // 2,097,152
    float* fusedB = W + 2097152;          // 2,097,152
    float* xzb    = W + 4194304;          // 8,388,608
    float* xcb    = W + 12582912;         // 4,194,304
    float* dtb    = W + 16777216;         // 4,194,304
    float* ygb    = W + 20971520;         // 4,194,304
    float* BCb    = W + 25165824;         // 262,144
    float* gates  = W + 25427968;         // 1,024
    float* Hinit  = W + 25445376;         // 1,048,576
    float* pmax   = W + 26493952;         // 16,384
    float* psum   = W + 26510336;         // 16,384
    float* xln = ygb;      // alias (dead before scan writes yg)
    float* tb  = xzb;      // alias (xz dead after scan)
    float* c1b = xcb;      // alias (xc dead after last scan)
    float* vb  = dtb;      // alias, spans dtb..ygb (8,388,608 floats)
    float* weff1 = BCb;             // 64*128*16 = 131072
    float* weff2 = BCb + 131072;    // 32*64*16  =  32768  (fits: 163840 < 262144)

    // CCE gates (independent of mamba chain)
    cce_gate_partial<<<dim3(16,2,16), 256, 0, stream>>>(orig_x, orig_y, cce_w1, pmax, psum);
    cce_gate_finish<<<16, 64, 0, stream>>>(pmax, psum, gates);

    const float* cur = fused_in;
    float* nxt = fusedA;
    for (int i = 0; i < 3; i++) {
        ln_kernel<<<NROWS, 64, 0, stream>>>(cur, m_ln_g + i*128, m_ln_b + i*128, xln, 0);
        gemm_bf16<128,128><<<dim3(128, 4), 256, 0, stream>>>(xln, m_in_w + (long)i*512*128, nullptr, xzb, 512);
        dwconv_silu<<<NROWS, 256, 0, stream>>>(xzb, m_conv_w + i*1024, m_conv_b + i*256, xcb);
        xproj_dt<<<NROWS, 256, 0, stream>>>(xcb, m_xproj_w + i*24*256, m_dt_w + i*2048, m_dt_b + i*256, dtb, BCb);
        scan_part<<<dim3(BB, NCH), 256, 0, stream>>>(dtb, xcb, BCb, m_Alog + i*2048, nxt);
        scan_mid<<<BB, 256, 0, stream>>>(nxt, Hinit);
        scan_fin<<<dim3(BB, NCH), 256, 0, stream>>>(dtb, xcb, BCb, xzb, m_Alog + i*2048, m_D + i*256, Hinit, ygb);
        gemm_bf16<256,64><<<dim3(256, 1), 256, 0, stream>>>(ygb, m_out_w + (long)i*128*256, cur, nxt, 128);
        cur = nxt;
        nxt = (i == 0) ? fusedB : fusedA;
    }
    // cur == fusedA here (A -> B -> A)
    ln_kernel<<<NROWS, 64, 0, stream>>>(cur, lnf_g, lnf_b, tb, 1);
    prep_weff<<<32, 256, 0, stream>>>(c1_w, weff1, 64*128);
    prep_weff<<<8, 256, 0, stream>>>(c2_w, weff2, 32*64);
    conv_up2_phase<128, 32, 16><<<dim3(4, 4, 16), 256, 0, stream>>>(tb, weff1, c1_b, bn1_g, bn1_b, bn1_m, bn1_v, c1b, 0, 64);
    conv_up2_phase<64, 64, 16><<<dim3(16, 2, 16), 256, 0, stream>>>(c1b, weff2, c2_b, bn2_g, bn2_b, bn2_m, bn2_v, vb, 1, 32);
    cce_add<<<dim3(64, 16), 256, 0, stream>>>(orig_x, orig_y, cce_w2, gates, vb);
    conv3_sig<<<dim3(64, 16), 256, 0, stream>>>(vb, c3_w, c3_b, (float*)d_out);
}

// Round 9
// 937.012 us; speedup vs baseline: 1.1254x; 1.1254x over previous
//
#include <hip/hip_runtime.h>
#include <hip/hip_bf16.h>

// ---------------- sizes ----------------
#define BB   16
#define LL   1024
#define DM   128
#define DIN  256
#define NST  8
#define NROWS (BB*LL)      // 16384
#define NCH  32
#define TCH  32
#define PSZ  1048576       // B*NCH*DIN*8

static __device__ __forceinline__ float sigmoidf_(float x){ return 1.f/(1.f+expf(-x)); }
static __device__ __forceinline__ float siluf_(float x){ return x/(1.f+expf(-x)); }
static __device__ __forceinline__ unsigned short f2bf(float f){
    union { float f; unsigned u; } v; v.f = f;
    unsigned r = v.u + 0x7fff + ((v.u >> 16) & 1);
    return (unsigned short)(r >> 16);
}

typedef __attribute__((ext_vector_type(8))) short short8;
typedef __attribute__((ext_vector_type(4))) float floatx4;

// ---------------- LayerNorm -> f32 (transpose for decoder) ----------------
__global__ __launch_bounds__(64) void ln_kernel(const float* __restrict__ X,
        const float* __restrict__ g, const float* __restrict__ b,
        float* __restrict__ Y, int transpose)
{
    int row = blockIdx.x;
    int t = threadIdx.x;
    float x0 = X[(long)row*DM + t];
    float x1 = X[(long)row*DM + 64 + t];
    float s = x0 + x1, ss = x0*x0 + x1*x1;
    #pragma unroll
    for (int off = 32; off; off >>= 1) { s += __shfl_down(s, off); ss += __shfl_down(ss, off); }
    s = __shfl(s, 0); ss = __shfl(ss, 0);
    float mean = s * (1.f/128.f);
    float var  = ss * (1.f/128.f) - mean*mean;
    float inv  = rsqrtf(var + 1e-5f);
    float y0 = (x0-mean)*inv*g[t]    + b[t];
    float y1 = (x1-mean)*inv*g[64+t] + b[64+t];
    if (!transpose) {
        Y[(long)row*DM + t] = y0;
        Y[(long)row*DM + 64 + t] = y1;
    } else {
        int bb = row >> 10, l = row & 1023;
        Y[((long)(bb*DM) + t)*LL + l] = y0;
        Y[((long)(bb*DM) + 64 + t)*LL + l] = y1;
    }
}

// ---------------- LayerNorm -> bf16 (feeds MFMA GEMM) ----------------
__global__ __launch_bounds__(64) void ln_bf16_kernel(const float* __restrict__ X,
        const float* __restrict__ g, const float* __restrict__ b,
        unsigned short* __restrict__ Y)
{
    int row = blockIdx.x;
    int t = threadIdx.x;
    float x0 = X[(long)row*DM + t];
    float x1 = X[(long)row*DM + 64 + t];
    float s = x0 + x1, ss = x0*x0 + x1*x1;
    #pragma unroll
    for (int off = 32; off; off >>= 1) { s += __shfl_down(s, off); ss += __shfl_down(ss, off); }
    s = __shfl(s, 0); ss = __shfl(ss, 0);
    float mean = s * (1.f/128.f);
    float var  = ss * (1.f/128.f) - mean*mean;
    float inv  = rsqrtf(var + 1e-5f);
    Y[(long)row*DM + t]      = f2bf((x0-mean)*inv*g[t]    + b[t]);
    Y[(long)row*DM + 64 + t] = f2bf((x1-mean)*inv*g[64+t] + b[64+t]);
}

// ---------------- bf16-MFMA GEMM: C[M,N] = A[M,K](bf16) @ W[N,K]^T(f32) (+S) ----------------
template<int K, int MT>
__global__ __launch_bounds__(256) void gemm_bf16(const unsigned short* __restrict__ A,
        const float* __restrict__ Wm, const float* __restrict__ S,
        float* __restrict__ C, int N)
{
    constexpr int NMT = MT/64;
    __shared__ unsigned short Als[MT][40];
    __shared__ unsigned short Bls[128][40];
    const int tid = threadIdx.x;
    const int m0 = blockIdx.x * MT;
    const int n0 = blockIdx.y * 128;
    const int lane = tid & 63, wv = tid >> 6;
    const int fr = lane & 15, quad = lane >> 4;
    floatx4 acc[NMT][8];
    #pragma unroll
    for (int mt = 0; mt < NMT; mt++)
        #pragma unroll
        for (int nt = 0; nt < 8; nt++) acc[mt][nt] = (floatx4){0.f,0.f,0.f,0.f};
    for (int kc = 0; kc < K; kc += 32) {
        __syncthreads();
        #pragma unroll
        for (int u = tid; u < MT*4; u += 256) {          // A: bf16 16B vector copy
            int row = u >> 2, seg = u & 3;
            // FIX (round-8 bug): uint4 = 16 B = 8 bf16 matches seg*8 element spacing.
            *(uint4*)&Als[row][seg*8] = *(const uint4*)&A[(long)(m0+row)*K + kc + seg*8];
        }
        #pragma unroll
        for (int u = tid; u < 1024; u += 256) {          // W: f32 -> bf16 packed
            int row = u >> 3, seg = u & 7;
            float4 v4 = *(const float4*)&Wm[(long)(n0+row)*K + kc + seg*4];
            uint2 pk;
            pk.x = (unsigned)f2bf(v4.x) | ((unsigned)f2bf(v4.y) << 16);
            pk.y = (unsigned)f2bf(v4.z) | ((unsigned)f2bf(v4.w) << 16);
            *(uint2*)&Bls[row][seg*4] = pk;
        }
        __syncthreads();
        short8 af[NMT];
        #pragma unroll
        for (int mt = 0; mt < NMT; mt++)
            af[mt] = *(const short8*)&Als[wv*(16*NMT) + mt*16 + fr][quad*8];
        #pragma unroll
        for (int nt = 0; nt < 8; nt++) {
            short8 bfv = *(const short8*)&Bls[nt*16 + fr][quad*8];
            #pragma unroll
            for (int mt = 0; mt < NMT; mt++)
                acc[mt][nt] = __builtin_amdgcn_mfma_f32_16x16x32_bf16(af[mt], bfv, acc[mt][nt], 0, 0, 0);
        }
    }
    const int rq = quad * 4;
    #pragma unroll
    for (int mt = 0; mt < NMT; mt++)
        #pragma unroll
        for (int nt = 0; nt < 8; nt++)
            #pragma unroll
            for (int r = 0; r < 4; r++) {
                long m = m0 + wv*(16*NMT) + mt*16 + rq + r;
                long n = n0 + nt*16 + fr;
                float v = acc[mt][nt][r];
                if (S) v += S[m*N + n];
                C[m*N + n] = v;
            }
}

// ---------------- fused depthwise conv+SiLU and x-proj/dt-proj/softplus ----------------
__global__ __launch_bounds__(256) void dwconv_xproj(const float* __restrict__ xz,
        const float* __restrict__ cw, const float* __restrict__ cb,
        const float* __restrict__ xproj_w, const float* __restrict__ dt_w,
        const float* __restrict__ dt_b, float* __restrict__ xc,
        float* __restrict__ dt_out, float* __restrict__ BC)
{
    __shared__ float xs[DIN];
    __shared__ float xdbl[24];
    int bl = blockIdx.x;            // b*1024 + l
    int d  = threadIdx.x;
    int l  = bl & 1023;
    float w0 = cw[d*4+0], w1 = cw[d*4+1], w2 = cw[d*4+2], w3 = cw[d*4+3];
    const float* base = xz + (long)bl*512 + d;
    float acc = cb[d] + w3 * base[0];
    if (l >= 1) acc += w2 * base[-512];
    if (l >= 2) acc += w1 * base[-1024];
    if (l >= 3) acc += w0 * base[-1536];
    float u = siluf_(acc);
    xs[d] = u;
    xc[(long)bl*DIN + d] = u;
    __syncthreads();
    int t = d;
    if (t < 192) {                       // 24 outputs x 8 lanes
        int e = t >> 3, j = t & 7;
        float p = 0.f;
        for (int k = j; k < DIN; k += 8) p += xs[k] * xproj_w[e*DIN + k];
        p += __shfl_down(p, 4, 8);
        p += __shfl_down(p, 2, 8);
        p += __shfl_down(p, 1, 8);
        if (j == 0) xdbl[e] = p;
    }
    __syncthreads();
    float v = dt_b[d];
    #pragma unroll
    for (int r = 0; r < 8; r++) v += xdbl[r] * dt_w[d*8 + r];
    v = (v > 20.f) ? v : log1pf(expf(v));           // softplus
    dt_out[(long)bl*DIN + d] = v;
    if (t < 16) BC[(long)bl*16 + t] = xdbl[8 + t];
}

// ---------------- chunked selective scan ----------------
__global__ __launch_bounds__(256) void scan_part(const float* __restrict__ dt,
        const float* __restrict__ xc, const float* __restrict__ BC,
        const float* __restrict__ Alog, float* __restrict__ PS)
{
    int b = blockIdx.x, c = blockIdx.y;
    int d = threadIdx.x;
    float a[NST], P[NST], S[NST];
    #pragma unroll
    for (int n = 0; n < NST; n++) { a[n] = -expf(Alog[d*NST + n]); P[n] = 1.f; S[n] = 0.f; }
    int t0 = c*TCH;
    const float* dtp = dt + ((long)b*LL + t0)*DIN + d;
    const float* up  = xc + ((long)b*LL + t0)*DIN + d;
    const float* bc  = BC + ((long)b*LL + t0)*16;
    for (int t = 0; t < TCH; t++) {
        float dtv = dtp[(long)t*DIN];
        float u   = up[(long)t*DIN];
        const float4* bc4 = (const float4*)(bc + t*16);
        float4 B0 = bc4[0], B1 = bc4[1];
        float Bv[NST] = {B0.x,B0.y,B0.z,B0.w,B1.x,B1.y,B1.z,B1.w};
        float dtu = dtv * u;
        #pragma unroll
        for (int n = 0; n < NST; n++) {
            float dA = __expf(dtv * a[n]);
            S[n] = dA * S[n] + dtu * Bv[n];
            P[n] *= dA;
        }
    }
    long o = (((long)b*NCH + c)*DIN + d)*8;
    #pragma unroll
    for (int n = 0; n < NST; n++) { PS[o + n] = P[n]; PS[PSZ + o + n] = S[n]; }
}

__global__ __launch_bounds__(256) void scan_mid(const float* __restrict__ PS,
        float* __restrict__ Hinit)
{
    int b = blockIdx.x;
    int d = threadIdx.x;
    float h[NST] = {};
    for (int c = 0; c < NCH; c++) {
        long o = (((long)b*NCH + c)*DIN + d)*8;
        #pragma unroll
        for (int n = 0; n < NST; n++) {
            Hinit[o + n] = h[n];
            h[n] = PS[o + n] * h[n] + PS[PSZ + o + n];
        }
    }
}

// Pass C writes yg as bf16 (feeds out-proj MFMA GEMM)
__global__ __launch_bounds__(256) void scan_fin(const float* __restrict__ dt,
        const float* __restrict__ xc, const float* __restrict__ BC,
        const float* __restrict__ xz, const float* __restrict__ Alog,
        const float* __restrict__ Dp, const float* __restrict__ Hinit,
        unsigned short* __restrict__ yg)
{
    int b = blockIdx.x, c = blockIdx.y;
    int d = threadIdx.x;
    float a[NST], h[NST];
    long o = (((long)b*NCH + c)*DIN + d)*8;
    #pragma unroll
    for (int n = 0; n < NST; n++) { a[n] = -expf(Alog[d*NST + n]); h[n] = Hinit[o + n]; }
    float Dpd = Dp[d];
    int t0 = c*TCH;
    const float* dtp = dt + ((long)b*LL + t0)*DIN + d;
    const float* up  = xc + ((long)b*LL + t0)*DIN + d;
    const float* bc  = BC + ((long)b*LL + t0)*16;
    const float* zp  = xz + ((long)b*LL + t0)*512 + 256 + d;
    unsigned short* yo = yg + ((long)b*LL + t0)*DIN + d;
    for (int t = 0; t < TCH; t++) {
        float dtv = dtp[(long)t*DIN];
        float u   = up[(long)t*DIN];
        const float4* bc4 = (const float4*)(bc + t*16);
        float4 B0 = bc4[0], B1 = bc4[1], C0 = bc4[2], C1 = bc4[3];
        float Bv[NST] = {B0.x,B0.y,B0.z,B0.w,B1.x,B1.y,B1.z,B1.w};
        float Cv[NST] = {C0.x,C0.y,C0.z,C0.w,C1.x,C1.y,C1.z,C1.w};
        float dtu = dtv * u;
        float y = 0.f;
        #pragma unroll
        for (int n = 0; n < NST; n++) {
            float dA = __expf(dtv * a[n]);
            h[n] = dA * h[n] + dtu * Bv[n];
            y += h[n] * Cv[n];
        }
        y += u * Dpd;
        float z = zp[(long)t*512];
        yo[(long)t*DIN] = f2bf(y * siluf_(z));
    }
}

// ---------------- phase-decomposed up2+3x3 conv (round-4 proven version) ----------------
__global__ void prep_weff(const float* __restrict__ Wr, float* __restrict__ We, int total)
{
    int t = blockIdx.x*256 + threadIdx.x;
    if (t >= total) return;
    float w[3][3];
    #pragma unroll
    for (int a = 0; a < 3; a++)
        #pragma unroll
        for (int c = 0; c < 3; c++) w[a][c] = Wr[(long)t*9 + a*3 + c];
    float cw[2][3][2];
    #pragma unroll
    for (int ky = 0; ky < 3; ky++) {
        cw[0][ky][0] = w[ky][0];           cw[0][ky][1] = w[ky][1] + w[ky][2];
        cw[1][ky][0] = w[ky][0] + w[ky][1]; cw[1][ky][1] = w[ky][2];
    }
    float* o = We + (long)t*16;   // [py][px][i*2+j]
    #pragma unroll
    for (int px = 0; px < 2; px++) {
        o[0*8+px*4+0] = cw[px][0][0];               o[0*8+px*4+1] = cw[px][0][1];
        o[0*8+px*4+2] = cw[px][1][0]+cw[px][2][0];  o[0*8+px*4+3] = cw[px][1][1]+cw[px][2][1];
        o[1*8+px*4+0] = cw[px][0][0]+cw[px][1][0];  o[1*8+px*4+1] = cw[px][0][1]+cw[px][1][1];
        o[1*8+px*4+2] = cw[px][2][0];               o[1*8+px*4+3] = cw[px][2][1];
    }
}

template<int CIN, int INW, int ICB>
__global__ __launch_bounds__(256) void conv_up2_phase(const float* __restrict__ X,
        const float* __restrict__ We, const float* __restrict__ bias,
        const float* __restrict__ bng, const float* __restrict__ bnb,
        const float* __restrict__ bnm, const float* __restrict__ bnv,
        float* __restrict__ Y, int relu_first, int COUT)
{
    constexpr int OUTW = 2*INW;
    constexpr int NXT  = OUTW/64;
    __shared__ float  src[ICB][6][34];
    __shared__ float4 wf[ICB][16][4];
    const int ys = blockIdx.x / NXT, xt = blockIdx.x % NXT;
    const int y0 = ys*8, x0 = xt*64;
    const int ocb = blockIdx.y * 16;
    const int b = blockIdx.z;
    const int tid = threadIdx.x;
    const int rel = tid & 63, ocq = tid >> 6;
    const int Xc = x0 + rel;
    const int px = Xc & 1;
    const int lcp = (rel >> 1) + px;
    const int ry0 = y0 >> 1;
    float acc[8][4] = {};
    for (int ic0 = 0; ic0 < CIN; ic0 += ICB) {
        __syncthreads();
        for (int i = tid; i < ICB*6*34; i += 256) {
            int ic = i / 204, rem = i % 204;
            int rr = rem / 34, cc = rem % 34;
            int gr = ry0 - 1 + rr, gc = (x0>>1) - 1 + cc;
            float v = 0.f;
            if ((unsigned)gr < (unsigned)INW && (unsigned)gc < (unsigned)INW)
                v = X[((long)(b*CIN + ic0+ic))*(INW*INW) + gr*INW + gc];
            src[ic][rr][cc] = v;
        }
        for (int i = tid; i < ICB*256; i += 256) {
            int ic = i >> 8, rem = i & 255;
            int ol = rem >> 4, k = rem & 15;
            ((float*)&wf[ic][ol][0])[k] = We[((long)(ocb+ol)*CIN + ic0+ic)*16 + k];
        }
        __syncthreads();
        for (int ic = 0; ic < ICB; ic++) {
            float s[6][2];
            #pragma unroll
            for (int r = 0; r < 6; r++) { s[r][0] = src[ic][r][lcp]; s[r][1] = src[ic][r][lcp+1]; }
            #pragma unroll
            for (int ol = 0; ol < 4; ol++) {
                float4 w0 = wf[ic][(ocq<<2)+ol][px];
                float4 w1 = wf[ic][(ocq<<2)+ol][2+px];
                #pragma unroll
                for (int p = 0; p < 4; p++) {
                    acc[2*p  ][ol] += w0.x*s[p  ][0] + w0.y*s[p  ][1] + w0.z*s[p+1][0] + w0.w*s[p+1][1];
                    acc[2*p+1][ol] += w1.x*s[p+1][0] + w1.y*s[p+1][1] + w1.z*s[p+2][0] + w1.w*s[p+2][1];
                }
            }
        }
    }
    #pragma unroll
    for (int ol = 0; ol < 4; ol++) {
        int oc = ocb + (ocq<<2) + ol;
        float bi = bias[oc];
        float sc = bng[oc] * rsqrtf(bnv[oc] + 1e-5f);
        float sh = bnb[oc] - bnm[oc]*sc;
        #pragma unroll
        for (int yy = 0; yy < 8; yy++) {
            float v = acc[yy][ol] + bi;
            v = relu_first ? (fmaxf(v, 0.f)*sc + sh) : fmaxf(v*sc + sh, 0.f);
            Y[((long)(b*COUT + oc))*(OUTW*OUTW) + (long)(y0+yy)*OUTW + Xc] = v;
        }
    }
}

// ---------------- CCE gate partials (tiled matvec) ----------------
__global__ __launch_bounds__(256) void cce_gate_partial(const float* __restrict__ ox,
        const float* __restrict__ oy, const float* __restrict__ w1,
        float* __restrict__ pmax, float* __restrict__ psum)
{
    __shared__ float xs[32*512];
    __shared__ float wl[32*32];
    __shared__ float rmx[4][32], rsm[4][32];
    const int sg = blockIdx.x;
    const int dir = blockIdx.y, b = blockIdx.z;
    const float* X = (dir == 0 ? ox : oy) + (long)b*524288;
    const int t = threadIdx.x;
    for (int i = t; i < 1024; i += 256) { int oc = i >> 5, ic = i & 31; wl[ic*32 + oc] = w1[i]; }
    const int ocg = t & 3, pslot = t >> 2;
    const int oc0 = ocg*8;
    float mx[8], sm[8];
    #pragma unroll
    for (int j = 0; j < 8; j++) { mx[j] = -1e30f; sm[j] = 0.f; }
    const int base = sg*1024;
    for (int tile = 0; tile < 2; tile++) {
        __syncthreads();
        const int p0 = base + tile*512;
        for (int i = t*4; i < 32*512; i += 1024) {
            int ic = i >> 9, px = i & 511;
            *(float4*)&xs[ic*512 + px] = *(const float4*)&X[(long)ic*16384 + p0 + px];
        }
        __syncthreads();
        float acc[8][8];
        #pragma unroll
        for (int p = 0; p < 8; p++)
            #pragma unroll
            for (int j = 0; j < 8; j++) acc[p][j] = 0.f;
        #pragma unroll
        for (int ic = 0; ic < 32; ic++) {
            float4 x0 = *(const float4*)&xs[ic*512 + pslot*4];
            float4 x1 = *(const float4*)&xs[ic*512 + 256 + pslot*4];
            float4 wa = *(const float4*)&wl[ic*32 + oc0];
            float4 wb = *(const float4*)&wl[ic*32 + oc0 + 4];
            float xv[8] = {x0.x,x0.y,x0.z,x0.w,x1.x,x1.y,x1.z,x1.w};
            float wv[8] = {wa.x,wa.y,wa.z,wa.w,wb.x,wb.y,wb.z,wb.w};
            #pragma unroll
            for (int p = 0; p < 8; p++)
                #pragma unroll
                for (int j = 0; j < 8; j++)
                    acc[p][j] += xv[p]*wv[j];
        }
        #pragma unroll
        for (int p = 0; p < 8; p++)
            #pragma unroll
            for (int j = 0; j < 8; j++) { mx[j] = fmaxf(mx[j], acc[p][j]); sm[j] += acc[p][j]; }
    }
    #pragma unroll
    for (int j = 0; j < 8; j++) {
        #pragma unroll
        for (int off = 32; off >= 4; off >>= 1) {
            mx[j] = fmaxf(mx[j], __shfl_down(mx[j], off));
            sm[j] += __shfl_down(sm[j], off);
        }
    }
    const int wave = t >> 6, lane = t & 63;
    __syncthreads();
    if (lane < 4) {
        #pragma unroll
        for (int j = 0; j < 8; j++) { rmx[wave][lane*8+j] = mx[j]; rsm[wave][lane*8+j] = sm[j]; }
    }
    __syncthreads();
    if (t < 32) {
        float M = fmaxf(fmaxf(rmx[0][t], rmx[1][t]), fmaxf(rmx[2][t], rmx[3][t]));
        float S = rsm[0][t] + rsm[1][t] + rsm[2][t] + rsm[3][t];
        long idx = ((long)(dir*16 + b)*32 + t)*16 + sg;
        pmax[idx] = M; psum[idx] = S;
    }
}

__global__ void cce_gate_finish(const float* __restrict__ pmax, const float* __restrict__ psum,
                                float* __restrict__ gates)
{
    int i = blockIdx.x*64 + threadIdx.x;
    if (i < 1024) {
        float M = -1e30f, S = 0.f;
        #pragma unroll
        for (int sg = 0; sg < 16; sg++) { M = fmaxf(M, pmax[i*16+sg]); S += psum[i*16+sg]; }
        gates[i] = sigmoidf_(M + S*(1.f/16384.f));
    }
}

// ---------------- CCE add ----------------
__global__ __launch_bounds__(256) void cce_add(const float* __restrict__ ox,
        const float* __restrict__ oy, const float* __restrict__ w2,
        const float* __restrict__ gates, float* __restrict__ v)
{
    __shared__ float w[32][32];
    int t = threadIdx.x;
    int b = blockIdx.y;
    int s = blockIdx.x*256 + t;
    for (int i = t; i < 1024; i += 256) w[i>>5][i&31] = w2[i];
    __syncthreads();
    const float* xb = ox + (long)b*524288;
    const float* yb = oy + (long)b*524288;
    float r1[32] = {}, r2[32] = {};
    for (int ic = 0; ic < 32; ic++) {
        float xv = xb[(long)ic*16384 + s];
        float yv = yb[(long)ic*16384 + s];
        #pragma unroll
        for (int oc = 0; oc < 32; oc++) { r1[oc] += w[oc][ic]*yv; r2[oc] += w[oc][ic]*xv; }
    }
    float* vb = v + (long)b*524288;
    const float* g1 = gates + b*32;
    const float* g2 = gates + 512 + b*32;
    #pragma unroll
    for (int oc = 0; oc < 32; oc++)
        vb[(long)oc*16384 + s] += g1[oc]*r1[oc] + g2[oc]*r2[oc];
}

// ---------------- conv3 3x3 (32->1) + sigmoid ----------------
__global__ __launch_bounds__(256) void conv3_sig(const float* __restrict__ v,
        const float* __restrict__ w3, const float* __restrict__ b3, float* __restrict__ out)
{
    __shared__ float w[288];
    int t = threadIdx.x;
    for (int i = t; i < 288; i += 256) w[i] = w3[i];
    __syncthreads();
    int b = blockIdx.y;
    int y = blockIdx.x*2 + (t >> 7);
    int x = t & 127;
    const float* vb = v + (long)b*524288;
    float acc = b3[0];
    for (int ic = 0; ic < 32; ic++) {
        const float* p = vb + (long)ic*16384;
        #pragma unroll
        for (int ky = 0; ky < 3; ky++) {
            int yy = y + ky - 1;
            if ((unsigned)yy >= 128u) continue;
            #pragma unroll
            for (int kx = 0; kx < 3; kx++) {
                int xx = x + kx - 1;
                if ((unsigned)xx >= 128u) continue;
                acc += w[ic*9 + ky*3 + kx] * p[yy*128 + xx];
            }
        }
    }
    out[(long)b*16384 + y*128 + x] = sigmoidf_(acc);
}

// ---------------- launch ----------------
extern "C" void kernel_launch(void* const* d_in, const int* in_sizes, int n_in,
                              void* d_out, int out_size, void* d_ws, size_t ws_size,
                              hipStream_t stream)
{
    const float* fused_in = (const float*)d_in[0];
    const float* orig_x   = (const float*)d_in[1];
    const float* orig_y   = (const float*)d_in[2];
    const float* m_ln_g   = (const float*)d_in[3];
    const float* m_ln_b   = (const float*)d_in[4];
    const float* m_in_w   = (const float*)d_in[5];
    const float* m_conv_w = (const float*)d_in[6];
    const float* m_conv_b = (const float*)d_in[7];
    const float* m_xproj_w= (const float*)d_in[8];
    const float* m_dt_w   = (const float*)d_in[9];
    const float* m_dt_b   = (const float*)d_in[10];
    const float* m_Alog   = (const float*)d_in[11];
    const float* m_D      = (const float*)d_in[12];
    const float* m_out_w  = (const float*)d_in[13];
    const float* lnf_g    = (const float*)d_in[14];
    const float* lnf_b    = (const float*)d_in[15];
    const float* c1_w     = (const float*)d_in[16];
    const float* c1_b     = (const float*)d_in[17];
    const float* bn1_g    = (const float*)d_in[18];
    const float* bn1_b    = (const float*)d_in[19];
    const float* bn1_m    = (const float*)d_in[20];
    const float* bn1_v    = (const float*)d_in[21];
    const float* c2_w     = (const float*)d_in[22];
    const float* c2_b     = (const float*)d_in[23];
    const float* bn2_g    = (const float*)d_in[24];
    const float* bn2_b    = (const float*)d_in[25];
    const float* bn2_m    = (const float*)d_in[26];
    const float* bn2_v    = (const float*)d_in[27];
    const float* cce_w1   = (const float*)d_in[28];
    const float* cce_w2   = (const float*)d_in[29];
    const float* c3_w     = (const float*)d_in[30];
    const float* c3_b     = (const float*)d_in[31];

    float* W = (float*)d_ws;
    float* fusedA = W;                    // 2,097,152
    float* fusedB = W + 2097152;          // 2,097,152
    float* xzb    = W + 4194304;          // 8,388,608
    float* xcb    = W + 12582912;         // 4,194,304
    float* dtb    = W + 16777216;         // 4,194,304
    float* ygb    = W + 20971520;         // 4,194,304 (holds bf16 xln / bf16 yg)
    float* BCb    = W + 25165824;         // 262,144
    float* gates  = W + 25427968;         // 1,024
    float* Hinit  = W + 25445376;         // 1,048,576
    float* pmax   = W + 26493952;         // 16,384
    float* psum   = W + 26510336;         // 16,384
    unsigned short* xlnb = (unsigned short*)ygb;   // 16384*128 bf16 (dead before yg written)
    unsigned short* ygbb = (unsigned short*)ygb;   // 16384*256 bf16
    float* tb  = xzb;      // alias (xz dead after scan)
    float* c1b = xcb;      // alias (xc dead after last scan)
    float* vb  = dtb;      // alias, spans dtb..ygb (8,388,608 floats)
    float* weff1 = BCb;             // 64*128*16 = 131072
    float* weff2 = BCb + 131072;    // 32*64*16  =  32768

    // CCE gates (independent of mamba chain)
    cce_gate_partial<<<dim3(16,2,16), 256, 0, stream>>>(orig_x, orig_y, cce_w1, pmax, psum);
    cce_gate_finish<<<16, 64, 0, stream>>>(pmax, psum, gates);

    const float* cur = fused_in;
    float* nxt = fusedA;
    for (int i = 0; i < 3; i++) {
        ln_bf16_kernel<<<NROWS, 64, 0, stream>>>(cur, m_ln_g + i*128, m_ln_b + i*128, xlnb);
        gemm_bf16<128,128><<<dim3(128, 4), 256, 0, stream>>>(xlnb, m_in_w + (long)i*512*128, nullptr, xzb, 512);
        dwconv_xproj<<<NROWS, 256, 0, stream>>>(xzb, m_conv_w + i*1024, m_conv_b + i*256,
                m_xproj_w + i*24*256, m_dt_w + i*2048, m_dt_b + i*256, xcb, dtb, BCb);
        scan_part<<<dim3(BB, NCH), 256, 0, stream>>>(dtb, xcb, BCb, m_Alog + i*2048, nxt);
        scan_mid<<<BB, 256, 0, stream>>>(nxt, Hinit);
        scan_fin<<<dim3(BB, NCH), 256, 0, stream>>>(dtb, xcb, BCb, xzb, m_Alog + i*2048, m_D + i*256, Hinit, ygbb);
        gemm_bf16<256,64><<<dim3(256, 1), 256, 0, stream>>>(ygbb, m_out_w + (long)i*128*256, cur, nxt, 128);
        cur = nxt;
        nxt = (i == 0) ? fusedB : fusedA;
    }
    // cur == fusedA here (A -> B -> A)
    ln_kernel<<<NROWS, 64, 0, stream>>>(cur, lnf_g, lnf_b, tb, 1);
    prep_weff<<<32, 256, 0, stream>>>(c1_w, weff1, 64*128);
    prep_weff<<<8, 256, 0, stream>>>(c2_w, weff2, 32*64);
    conv_up2_phase<128, 32, 16><<<dim3(8, 4, 16), 256, 0, stream>>>(tb, weff1, c1_b, bn1_g, bn1_b, bn1_m, bn1_v, c1b, 0, 64);
    conv_up2_phase<64, 64, 16><<<dim3(32, 2, 16), 256, 0, stream>>>(c1b, weff2, c2_b, bn2_g, bn2_b, bn2_m, bn2_v, vb, 1, 32);
    cce_add<<<dim3(64, 16), 256, 0, stream>>>(orig_x, orig_y, cce_w2, gates, vb);
    conv3_sig<<<dim3(64, 16), 256, 0, stream>>>(vb, c3_w, c3_b, (float*)d_out);
}